// Round 9
// baseline (230.555 us; speedup 1.0000x reference)
//
#include <hip/hip_runtime.h>
#include <math.h>

#define DIM 3072
#define SEQ 8192
#define NROWS (3 * DIM)      // 9216 GEMV output rows
#define NBLK 1024            // 4 blocks/CU x 256 CUs, co-resident (proven R4/R6)
#define NWAVE (NBLK * 4)     // 4096 waves

__device__ __forceinline__ float silu_f(float v) {
    return v / (1.0f + __expf(-v));
}

// Fully fused, one dispatch:
//   GEMV (W-stream) -> LN stats (x-stream, keeps only sum/sq) ->
//   release+poll sync -> stage scale/shift to LDS -> apply (x re-read from L3).
// Sync lessons: poll = atomic RMW (coherence-point read, never L1-stale),
// one poller/block, s_sleep between polls, ONE acquire fence after.
// Spill lesson: nothing bigger than 4 scalars lives across the wait.
__global__ __launch_bounds__(256, 4) void fused_adaln_kernel(
    const float* __restrict__ x, const float* __restrict__ emb,
    const float* __restrict__ W, const float* __restrict__ b,
    float* __restrict__ out, float* __restrict__ gate,
    float* __restrict__ shift, float* __restrict__ scale,
    unsigned int* __restrict__ counter)
{
    __shared__ float s_a[DIM];   // silu(emb) during GEMV; scale after sync
    __shared__ float s_b[DIM];   // shift after sync
    const int t = threadIdx.x;
    const int wid = t >> 6;
    const int lane = t & 63;
    const int wgid = blockIdx.x * 4 + wid;     // 0..NWAVE-1

    // ---- stage silu(emb) into LDS ----
    {
        const float4* emb4 = (const float4*)emb;
        float4* sa4 = (float4*)s_a;
        #pragma unroll
        for (int k = 0; k < 3; ++k) {
            int i = t + k * 256;               // float4 index < 768
            float4 v = emb4[i];
            v.x = silu_f(v.x); v.y = silu_f(v.y);
            v.z = silu_f(v.z); v.w = silu_f(v.w);
            sa4[i] = v;
        }
    }
    __syncthreads();

    // ---- GEMV: rows wgid, wgid+NWAVE, (wgid+2*NWAVE if < NROWS) ----
    {
        const float4* s4 = (const float4*)s_a;
        for (int row = wgid; row < NROWS; row += NWAVE) {
            const float4* w4 = (const float4*)(W + (size_t)row * DIM);
            float acc = 0.f;
            #pragma unroll
            for (int k = 0; k < 12; ++k) {
                float4 w = w4[lane + 64 * k];
                float4 v = s4[lane + 64 * k];
                acc += w.x * v.x + w.y * v.y + w.z * v.z + w.w * v.w;
            }
            #pragma unroll
            for (int off = 32; off > 0; off >>= 1)
                acc += __shfl_xor(acc, off, 64);
            if (lane == 0) {
                float e = acc + b[row];
                int i = row / 3;
                int r = row - 3 * i;
                if (r == 0)      shift[i] = e;
                else if (r == 1) scale[i] = e;
                else             gate[i]  = e;
            }
        }
    }

    // ---- LN stats for rows wgid and wgid+NWAVE (keep 4 scalars only) ----
    float mean0, rstd0, mean1, rstd1;
    {
        const float4* xr = (const float4*)(x + (size_t)wgid * DIM);
        float sum = 0.f, sq = 0.f;
        #pragma unroll
        for (int k = 0; k < 12; ++k) {
            float4 v = xr[lane + 64 * k];
            sum += v.x + v.y + v.z + v.w;
            sq  += v.x * v.x + v.y * v.y + v.z * v.z + v.w * v.w;
        }
        #pragma unroll
        for (int off = 32; off > 0; off >>= 1) {
            sum += __shfl_xor(sum, off, 64);
            sq  += __shfl_xor(sq,  off, 64);
        }
        mean0 = sum * (1.0f / DIM);
        rstd0 = rsqrtf(sq * (1.0f / DIM) - mean0 * mean0 + 1e-6f);
    }
    {
        const float4* xr = (const float4*)(x + (size_t)(wgid + NWAVE) * DIM);
        float sum = 0.f, sq = 0.f;
        #pragma unroll
        for (int k = 0; k < 12; ++k) {
            float4 v = xr[lane + 64 * k];
            sum += v.x + v.y + v.z + v.w;
            sq  += v.x * v.x + v.y * v.y + v.z * v.z + v.w * v.w;
        }
        #pragma unroll
        for (int off = 32; off > 0; off >>= 1) {
            sum += __shfl_xor(sum, off, 64);
            sq  += __shfl_xor(sq,  off, 64);
        }
        mean1 = sum * (1.0f / DIM);
        rstd1 = rsqrtf(sq * (1.0f / DIM) - mean1 * mean1 + 1e-6f);
    }

    // ---- publish (release: flushes this block's shift/scale/gate) ----
    __syncthreads();
    if (t == 0) {
        __hip_atomic_fetch_add(counter, 1u, __ATOMIC_RELEASE,
                               __HIP_MEMORY_SCOPE_AGENT);
        // poll at the coherence point: atomic RMW can't read a stale L1 line
        while (__hip_atomic_fetch_add(counter, 0u, __ATOMIC_RELAXED,
                                      __HIP_MEMORY_SCOPE_AGENT) < (unsigned)NBLK)
            __builtin_amdgcn_s_sleep(16);
    }
    __syncthreads();
    __builtin_amdgcn_fence(__ATOMIC_ACQUIRE, "agent");

    // ---- stage scale/shift into LDS (silu buffer is dead now) ----
    {
        const float4* scg = (const float4*)scale;
        const float4* shg = (const float4*)shift;
        float4* sa4 = (float4*)s_a;
        float4* sb4 = (float4*)s_b;
        #pragma unroll
        for (int k = 0; k < 3; ++k) {
            int i = t + k * 256;
            sa4[i] = scg[i];
            sb4[i] = shg[i];
        }
    }
    __syncthreads();
    const float4* lsc = (const float4*)s_a;
    const float4* lsh = (const float4*)s_b;

    // ---- apply row wgid (x re-read: L3-resident, just streamed) ----
    {
        const float4* xr = (const float4*)(x + (size_t)wgid * DIM);
        float4* o4 = (float4*)(out + (size_t)wgid * DIM);
        #pragma unroll
        for (int k = 0; k < 12; ++k) {
            int i = lane + 64 * k;
            float4 v = xr[i];
            float4 sc = lsc[i];
            float4 sh = lsh[i];
            float4 r;
            r.x = (v.x - mean0) * rstd0 * sc.x + sh.x;
            r.y = (v.y - mean0) * rstd0 * sc.y + sh.y;
            r.z = (v.z - mean0) * rstd0 * sc.z + sh.z;
            r.w = (v.w - mean0) * rstd0 * sc.w + sh.w;
            o4[i] = r;
        }
    }
    // ---- apply row wgid+NWAVE ----
    {
        const float4* xr = (const float4*)(x + (size_t)(wgid + NWAVE) * DIM);
        float4* o4 = (float4*)(out + (size_t)(wgid + NWAVE) * DIM);
        #pragma unroll
        for (int k = 0; k < 12; ++k) {
            int i = lane + 64 * k;
            float4 v = xr[i];
            float4 sc = lsc[i];
            float4 sh = lsh[i];
            float4 r;
            r.x = (v.x - mean1) * rstd1 * sc.x + sh.x;
            r.y = (v.y - mean1) * rstd1 * sc.y + sh.y;
            r.z = (v.z - mean1) * rstd1 * sc.z + sh.z;
            r.w = (v.w - mean1) * rstd1 * sc.w + sh.w;
            o4[i] = r;
        }
    }
}

extern "C" void kernel_launch(void* const* d_in, const int* in_sizes, int n_in,
                              void* d_out, int out_size, void* d_ws, size_t ws_size,
                              hipStream_t stream) {
    const float* x   = (const float*)d_in[0];  // [1, 8192, 3072]
    const float* emb = (const float*)d_in[1];  // [1, 3072]
    const float* W   = (const float*)d_in[2];  // [9216, 3072]
    const float* b   = (const float*)d_in[3];  // [9216]
    float* out   = (float*)d_out;                      // [1,8192,3072] flat
    float* gate  = out + (size_t)SEQ * DIM;            // [1,3072] appended
    float* shift = (float*)d_ws;                       // [3072]
    float* scale = shift + DIM;                        // [3072]
    unsigned int* counter = (unsigned int*)(scale + DIM);

    hipMemsetAsync(counter, 0, sizeof(unsigned int), stream);
    fused_adaln_kernel<<<NBLK, 256, 0, stream>>>(x, emb, W, b, out, gate,
                                                 shift, scale, counter);
}